// Round 6
// baseline (148.742 us; speedup 1.0000x reference)
//
#include <hip/hip_runtime.h>
#include <hip/hip_bf16.h>
#include <stdint.h>

// Fastfood 2D conv, MI355X. fp32 I/O:
// input (16,256,32,32), B/G/S (1,4096), bias (512), P (4096) i32 -> out (16,512,32,32).
// Per pixel: patch j=kk*256+ch (2304, pad 4096), *B, FWHT4096, perm P, *G, FWHT4096,
// *S[0:512]+bias.
//
// R4: pixel QUADS (ow = p, p+8, p+16, p+24), 4 px per uint2 LDS slot (b64 exchanges).
// R5: fp16-native pipeline (h2 regs, v_pk_add_f16 butterflies, bitcast exchanges).
// R6: WAR-barrier elimination (own-partition write-backs).
// R7: truncated second FWHT (pass1 reordered C->B->A-truncated); outputs born
//     per-thread: thread t owns oc=t (sum) and oc=256+t (alt-sum).
// R8: (a) SINGLE KERNEL: S*x+bias applied in-register, f32 scalars stored directly
//     to out (ws round-trip + finish launch gone). Output lines fill within one
//     block's lifetime -> L2 write-combines partial-line stores.
//     (b) Barriers 6 -> 4 per quad: B<->C exchanges (both passes) stay within
//     groups of 16 CONTIGUOUS threads (fixed t1) = intra-wave; lgkmcnt ordering
//     (compiler-inserted) suffices, no __syncthreads needed. Only cross-wave
//     A<->B exchanges and the arbitrary perm gather keep barriers.
//     (c) Tap reads 36 ds_read_u16 -> 9 ds_read_b64: s_in regrouped as
//     [kh][iw&7][ch] uint2 = {(v_iw, v_iw+16), (v_iw+8, v_iw+24)} so one b64 read
//     delivers a tap for all 4 quad pixels in h2 form; B-multiply is v_pk_mul_f16.
//     Boundary taps (p=0/kw=0 -> iw=-1; p=7/kw=2 -> iw=8) repack with uniform
//     branches. Staging-write bank conflicts also drop ~16-way -> ~4-way.
// LDS: 48 KiB s_in + 32 KiB buf = 80 KiB -> 2 blocks/CU.

typedef _Float16 h2 __attribute__((ext_vector_type(2)));

__device__ __forceinline__ uint16_t f2h16(float f) {
    union { _Float16 h; uint16_t u; } c; c.h = (_Float16)f; return c.u;
}
__device__ __forceinline__ int swz(int j) {
    return j ^ ((j >> 5) & 7) ^ (((j >> 8) & 1) * 24) ^ (((j >> 9) & 1) * 8);
}
__device__ __forceinline__ uint32_t h2u(h2 v) {
    union { h2 h; uint32_t u; } c; c.h = v; return c.u;
}
__device__ __forceinline__ h2 u2h(uint32_t x) {
    union { h2 h; uint32_t u; } c; c.u = x; return c.h;
}
__device__ __forceinline__ h2 pkh(float a, float b) {
    h2 r; r.x = (_Float16)a; r.y = (_Float16)b; return r;
}
__device__ __forceinline__ void h16h(h2* x) {
    #pragma unroll
    for (int h = 1; h < 16; h <<= 1) {
        #pragma unroll
        for (int g = 0; g < 16; g += 2 * h) {
            #pragma unroll
            for (int u = g; u < g + h; ++u) {
                h2 a = x[u], b = x[u + h];
                x[u]     = a + b;   // -> v_pk_add_f16
                x[u + h] = a - b;
            }
        }
    }
}
// truncated stride-256 round: s = sum_r x[r], d = sum_r (-1)^r x[r]
__device__ __forceinline__ void trunc16(const h2* x, h2& s, h2& d) {
    h2 sp[8], sm[8];
    #pragma unroll
    for (int i = 0; i < 8; ++i) {
        sp[i] = x[2 * i] + x[2 * i + 1];
        sm[i] = x[2 * i] - x[2 * i + 1];
    }
    #pragma unroll
    for (int h = 4; h >= 1; h >>= 1) {
        #pragma unroll
        for (int i = 0; i < h; ++i) { sp[i] = sp[i] + sp[i + h]; sm[i] = sm[i] + sm[i + h]; }
    }
    s = sp[0]; d = sm[0];
}

__global__ __launch_bounds__(256, 2)
void fastfood_kernel(const float* __restrict__ in,
                     const float* __restrict__ Bm,
                     const float* __restrict__ Gm,
                     const float* __restrict__ Sm,
                     const float* __restrict__ bias,
                     const int* __restrict__ P,
                     float* __restrict__ out)
{
    // s_in: [kh(3)][iwm(8)][ch(256)] of uint2 = {(v_iwm, v_iwm+16),(v_iwm+8, v_iwm+24)} f16.
    __shared__ uint16_t s_in[3 * 8 * 256 * 4];   // 48 KiB
    __shared__ uint2    buf2[4096];              // swizzled 4-pixel fp16 exchange, 32 KiB

    const int t  = threadIdx.x;
    const int t1 = t >> 4, t0 = t & 15;
    const int b  = blockIdx.x >> 5;
    const int oh = blockIdx.x & 31;

    // ---- stage input rows oh-1..oh+1 into LDS (coalesced float4 reads)
    // value at column iw goes to u16 slot map[iw>>3] of group iw&7:
    // slot order within uint2: 0=v(g), 1=v(g+16), 2=v(g+8), 3=v(g+24)
    #pragma unroll
    for (int i = 0; i < 24; ++i) {
        const int idx   = t + i * 256;
        const int part  = idx & 7;
        const int ch    = (idx >> 3) & 255;
        const int ihrel = idx >> 11;
        const int ih    = oh - 1 + ihrel;
        float4 ld = make_float4(0.f, 0.f, 0.f, 0.f);
        if ((unsigned)ih < 32u) {
            ld = *reinterpret_cast<const float4*>(
                in + ((((size_t)b * 256 + ch) * 32 + ih) * 32 + part * 4));
        }
        const int q    = part >> 1;                  // iw>>3 for this float4
        const int slot = (q == 0) ? 0 : (q == 1) ? 2 : (q == 2) ? 1 : 3;
        const int g0   = 4 * (part & 1);             // iwm of ld.x
        const int base = (ihrel * 8 + g0) * 1024 + ch * 4 + slot;
        s_in[base       ] = f2h16(ld.x);
        s_in[base + 1024] = f2h16(ld.y);
        s_in[base + 2048] = f2h16(ld.z);
        s_in[base + 3072] = f2h16(ld.w);
    }

    // ---- constants (per-lane vectorized where possible)
    float Bf[9];
    #pragma unroll
    for (int r = 0; r < 9; ++r) Bf[r] = Bm[r * 256 + t];
    h2 Bh[9];
    #pragma unroll
    for (int r = 0; r < 9; ++r) Bh[r] = pkh(Bf[r], Bf[r]);

    h2 Gh[16]; int PAv[16];
    #pragma unroll
    for (int q = 0; q < 4; ++q) {
        const int4   pv = *reinterpret_cast<const int4*>(P + 16 * t + 4 * q);
        const float4 gv = *reinterpret_cast<const float4*>(Gm + 16 * t + 4 * q);
        PAv[4 * q + 0] = swz(pv.x); PAv[4 * q + 1] = swz(pv.y);
        PAv[4 * q + 2] = swz(pv.z); PAv[4 * q + 3] = swz(pv.w);
        Gh[4 * q + 0] = pkh(gv.x, gv.x); Gh[4 * q + 1] = pkh(gv.y, gv.y);
        Gh[4 * q + 2] = pkh(gv.z, gv.z); Gh[4 * q + 3] = pkh(gv.w, gv.w);
    }
    const float St = Sm[t],       Ct = bias[t];
    const float Sd = Sm[256 + t], Cd = bias[256 + t];
    const size_t r0 = ((size_t)b * 512 + t) * 1024 + (size_t)oh * 32;
    const size_t r1 = r0 + (size_t)256 * 1024;
    __syncthreads();

    const uint2* s2 = reinterpret_cast<const uint2*>(s_in);

    for (int p = 0; p < 8; ++p) {             // pixel quad (ow = p, p+8, p+16, p+24)
        h2 x0[16], x1[16];                    // x0=(p, p+16), x1=(p+8, p+24)
        #pragma unroll
        for (int r = 0; r < 9; ++r) {
            const int kh = r / 3, kw = r % 3;
            const int iw = p - 1 + kw;        // in [-1, 8]
            const int g  = iw & 7;
            const uint2 u = s2[(kh * 8 + g) * 256 + t];
            h2 a = u2h(u.x), c = u2h(u.y);    // a=(v_g, v_g+16), c=(v_g+8, v_g+24)
            h2 ta = a, tc = c;
            if (iw < 0) {                     // p=0,kw=0: x0=(0,v15), x1=(v7,v23)
                ta.x = (_Float16)0.f; ta.y = c.x;
                tc = a;
            } else if (iw > 7) {              // p=7,kw=2: x0=(v8,v24), x1=(v16,0)
                ta = c;
                tc.x = a.y; tc.y = (_Float16)0.f;
            }
            x0[r] = Bh[r] * ta;               // -> v_pk_mul_f16
            x1[r] = Bh[r] * tc;
        }
        #pragma unroll
        for (int r = 9; r < 16; ++r) {
            x0[r] = pkh(0.f, 0.f);
            x1[r] = pkh(0.f, 0.f);
        }

        // ===== pass 0: A(str256) -> B(str16) -> C(str1), stage C-layout for gather
        h16h(x0); h16h(x1);                   // round A
        #pragma unroll                        // own slots (only thread t touches (r,t))
        for (int r = 0; r < 16; ++r)
            buf2[swz(256 * r + t)] = make_uint2(h2u(x0[r]), h2u(x1[r]));
        __syncthreads();                      // RAW, cross-wave (A -> B)
        #pragma unroll
        for (int r = 0; r < 16; ++r) {
            const uint2 u = buf2[swz(256 * t1 + 16 * r + t0)];
            x0[r] = u2h(u.x); x1[r] = u2h(u.y);
        }
        h16h(x0); h16h(x1);                   // round B
        #pragma unroll                        // own slots
        for (int r = 0; r < 16; ++r)
            buf2[swz(256 * t1 + 16 * r + t0)] = make_uint2(h2u(x0[r]), h2u(x1[r]));
        // NO barrier: B->C exchange lives in group t1's 256 slots, owned by
        // threads 16*t1..16*t1+15 = contiguous = same wave; lgkmcnt orders it.
        #pragma unroll
        for (int r = 0; r < 16; ++r) {
            const uint2 u = buf2[swz(256 * t1 + 16 * t0 + r)];
            x0[r] = u2h(u.x); x1[r] = u2h(u.y);
        }
        h16h(x0); h16h(x1);                   // round C
        #pragma unroll                        // own slots (stage for gather)
        for (int r = 0; r < 16; ++r)
            buf2[swz(256 * t1 + 16 * t0 + r)] = make_uint2(h2u(x0[r]), h2u(x1[r]));
        __syncthreads();                      // RAW, cross-wave (before perm gather)

        // ===== permutation + G: gather INTO C-layout (thread t owns j = 16t+r)
        #pragma unroll
        for (int r = 0; r < 16; ++r) {
            const uint2 u = buf2[PAv[r]];
            x0[r] = Gh[r] * u2h(u.x);
            x1[r] = Gh[r] * u2h(u.y);
        }

        // ===== pass 1 (reordered): C(str1) -> B(str16) -> A(str256, truncated)
        h16h(x0); h16h(x1);                   // round C'
        __syncthreads();                      // WAR: all gathers done before overwrite
        #pragma unroll
        for (int r = 0; r < 16; ++r)
            buf2[swz(256 * t1 + 16 * t0 + r)] = make_uint2(h2u(x0[r]), h2u(x1[r]));
        // NO barrier: C->B exchange intra-wave (group t1), as above.
        #pragma unroll
        for (int r = 0; r < 16; ++r) {
            const uint2 u = buf2[swz(256 * t1 + 16 * r + t0)];
            x0[r] = u2h(u.x); x1[r] = u2h(u.y);
        }
        h16h(x0); h16h(x1);                   // round B'
        #pragma unroll                        // own slots
        for (int r = 0; r < 16; ++r)
            buf2[swz(256 * t1 + 16 * r + t0)] = make_uint2(h2u(x0[r]), h2u(x1[r]));
        __syncthreads();                      // RAW, cross-wave (B' -> A-layout read)
        #pragma unroll
        for (int r = 0; r < 16; ++r) {        // A-layout: x[r] = j = 256r + t
            const uint2 u = buf2[swz(256 * r + t)];
            x0[r] = u2h(u.x); x1[r] = u2h(u.y);
        }
        // truncated round A: oc = t (sum), oc = 256+t (alternating sum)
        h2 s0, d0, s1, d1;
        trunc16(x0, s0, d0);                  // (ow p, p+16)
        trunc16(x1, s1, d1);                  // (ow p+8, p+24)

        // ---- direct epilogue: S*x + bias, f32 stores (lines fill within block life)
        out[r0 + p]      = St * (float)s0.x + Ct;
        out[r0 + p +  8] = St * (float)s1.x + Ct;
        out[r0 + p + 16] = St * (float)s0.y + Ct;
        out[r0 + p + 24] = St * (float)s1.y + Ct;
        out[r1 + p]      = Sd * (float)d0.x + Cd;
        out[r1 + p +  8] = Sd * (float)d1.x + Cd;
        out[r1 + p + 16] = Sd * (float)d0.y + Cd;
        out[r1 + p + 24] = Sd * (float)d1.y + Cd;
        // next quad's A-write hits thread-own slots -> no WAR barrier at loop top
    }
}

extern "C" void kernel_launch(void* const* d_in, const int* in_sizes, int n_in,
                              void* d_out, int out_size, void* d_ws, size_t ws_size,
                              hipStream_t stream) {
    const float* in   = (const float*)d_in[0];
    const float* Bm   = (const float*)d_in[1];
    const float* Gm   = (const float*)d_in[2];
    const float* Sm   = (const float*)d_in[3];
    const float* bias = (const float*)d_in[4];
    const int*   P    = (const int*)d_in[5];
    float* out = (float*)d_out;
    (void)d_ws; (void)ws_size;

    dim3 grid(16 * 32), block(256);
    fastfood_kernel<<<grid, block, 0, stream>>>(in, Bm, Gm, Sm, bias, P, out);
}

// Round 7
// 125.781 us; speedup vs baseline: 1.1825x; 1.1825x over previous
//
#include <hip/hip_runtime.h>
#include <hip/hip_bf16.h>
#include <stdint.h>

// Fastfood 2D conv, MI355X. fp32 I/O:
// input (16,256,32,32), B/G/S (1,4096), bias (512), P (4096) i32 -> out (16,512,32,32).
// Per pixel: patch j=kk*256+ch (2304, pad 4096), *B, FWHT4096, perm P, *G, FWHT4096,
// *S[0:512]+bias.
//
// R4: pixel QUADS (ow = p, p+8, p+16, p+24), 4 px per uint2 LDS slot (b64 exchanges).
// R5: fp16-native pipeline (h2 regs, v_pk_add_f16 butterflies, bitcast exchanges).
// R6: WAR-barrier elimination (own-partition write-backs).
// R7: truncated second FWHT; thread t owns oc=t (sum) and oc=256+t (alt-sum).
// R8: b64 tap reads ([kh][iw&7][ch] uint2 s_in layout); intra-wave B<->C exchanges
//     without barriers (4 barriers/quad); single kernel.
// R9: FIX R8's store amplification (WRITE_SIZE 251MB, L2 did RMW on 4B@4KB-stride
//     scalars). Outputs accumulate in REGISTERS across all 8 quads (p-loop fully
//     unrolled -> os[8]/od[8] stay in VGPRs), then ONE block-end epilogue:
//     register repack to ow-major (32 v_pack), XOR-swizzled b64 staging into buf2
//     (512 rows x 8 uint2 = exactly 4096 slots; i^((t>>1)&7) -> 4-cycle-optimal
//     b64 banking both phases), barrier, 16 iters of {b64 read, 4 cvt+FMA(S,bias),
//     float4 store}: 8 rows x full 128B lines per wave-instr. Output written once,
//     coalesced. No ws, no second kernel. +2 barriers per block total.
// LDS: 48 KiB s_in + 32 KiB buf = 80 KiB -> 2 blocks/CU.

typedef _Float16 h2 __attribute__((ext_vector_type(2)));

__device__ __forceinline__ uint16_t f2h16(float f) {
    union { _Float16 h; uint16_t u; } c; c.h = (_Float16)f; return c.u;
}
__device__ __forceinline__ int swz(int j) {
    return j ^ ((j >> 5) & 7) ^ (((j >> 8) & 1) * 24) ^ (((j >> 9) & 1) * 8);
}
__device__ __forceinline__ uint32_t h2u(h2 v) {
    union { h2 h; uint32_t u; } c; c.h = v; return c.u;
}
__device__ __forceinline__ h2 u2h(uint32_t x) {
    union { h2 h; uint32_t u; } c; c.u = x; return c.h;
}
__device__ __forceinline__ h2 pkh(float a, float b) {
    h2 r; r.x = (_Float16)a; r.y = (_Float16)b; return r;
}
__device__ __forceinline__ void h16h(h2* x) {
    #pragma unroll
    for (int h = 1; h < 16; h <<= 1) {
        #pragma unroll
        for (int g = 0; g < 16; g += 2 * h) {
            #pragma unroll
            for (int u = g; u < g + h; ++u) {
                h2 a = x[u], b = x[u + h];
                x[u]     = a + b;   // -> v_pk_add_f16
                x[u + h] = a - b;
            }
        }
    }
}
// truncated stride-256 round: s = sum_r x[r], d = sum_r (-1)^r x[r]
__device__ __forceinline__ void trunc16(const h2* x, h2& s, h2& d) {
    h2 sp[8], sm[8];
    #pragma unroll
    for (int i = 0; i < 8; ++i) {
        sp[i] = x[2 * i] + x[2 * i + 1];
        sm[i] = x[2 * i] - x[2 * i + 1];
    }
    #pragma unroll
    for (int h = 4; h >= 1; h >>= 1) {
        #pragma unroll
        for (int i = 0; i < h; ++i) { sp[i] = sp[i] + sp[i + h]; sm[i] = sm[i] + sm[i + h]; }
    }
    s = sp[0]; d = sm[0];
}
// slot k of a quad's packed output pair {s0,s1}: k=0->s0.x(ow p), 1->s1.x(p+8),
// 2->s0.y(p+16), 3->s1.y(p+24). k is compile-time under unroll.
__device__ __forceinline__ _Float16 slotk(const uint2& u, int k) {
    const h2 a = u2h(u.x), c = u2h(u.y);
    return (k == 0) ? a.x : (k == 1) ? c.x : (k == 2) ? a.y : c.y;
}

__global__ __launch_bounds__(256, 2)
void fastfood_kernel(const float* __restrict__ in,
                     const float* __restrict__ Bm,
                     const float* __restrict__ Gm,
                     const float* __restrict__ Sm,
                     const float* __restrict__ bias,
                     const int* __restrict__ P,
                     float* __restrict__ out)
{
    // s_in: [kh(3)][iwm(8)][ch(256)] of uint2 = {(v_iwm, v_iwm+16),(v_iwm+8, v_iwm+24)} f16.
    __shared__ uint16_t s_in[3 * 8 * 256 * 4];   // 48 KiB
    __shared__ uint2    buf2[4096];              // swizzled 4-pixel fp16 exchange, 32 KiB

    const int t  = threadIdx.x;
    const int t1 = t >> 4, t0 = t & 15;
    const int b  = blockIdx.x >> 5;
    const int oh = blockIdx.x & 31;

    // ---- stage input rows oh-1..oh+1 into LDS (coalesced float4 reads)
    #pragma unroll
    for (int i = 0; i < 24; ++i) {
        const int idx   = t + i * 256;
        const int part  = idx & 7;
        const int ch    = (idx >> 3) & 255;
        const int ihrel = idx >> 11;
        const int ih    = oh - 1 + ihrel;
        float4 ld = make_float4(0.f, 0.f, 0.f, 0.f);
        if ((unsigned)ih < 32u) {
            ld = *reinterpret_cast<const float4*>(
                in + ((((size_t)b * 256 + ch) * 32 + ih) * 32 + part * 4));
        }
        const int q    = part >> 1;                  // iw>>3 for this float4
        const int slot = (q == 0) ? 0 : (q == 1) ? 2 : (q == 2) ? 1 : 3;
        const int g0   = 4 * (part & 1);             // iwm of ld.x
        const int base = (ihrel * 8 + g0) * 1024 + ch * 4 + slot;
        s_in[base       ] = f2h16(ld.x);
        s_in[base + 1024] = f2h16(ld.y);
        s_in[base + 2048] = f2h16(ld.z);
        s_in[base + 3072] = f2h16(ld.w);
    }

    // ---- constants
    float Bf[9];
    #pragma unroll
    for (int r = 0; r < 9; ++r) Bf[r] = Bm[r * 256 + t];
    h2 Bh[9];
    #pragma unroll
    for (int r = 0; r < 9; ++r) Bh[r] = pkh(Bf[r], Bf[r]);

    h2 Gh[16]; int PAv[16];
    #pragma unroll
    for (int q = 0; q < 4; ++q) {
        const int4   pv = *reinterpret_cast<const int4*>(P + 16 * t + 4 * q);
        const float4 gv = *reinterpret_cast<const float4*>(Gm + 16 * t + 4 * q);
        PAv[4 * q + 0] = swz(pv.x); PAv[4 * q + 1] = swz(pv.y);
        PAv[4 * q + 2] = swz(pv.z); PAv[4 * q + 3] = swz(pv.w);
        Gh[4 * q + 0] = pkh(gv.x, gv.x); Gh[4 * q + 1] = pkh(gv.y, gv.y);
        Gh[4 * q + 2] = pkh(gv.z, gv.z); Gh[4 * q + 3] = pkh(gv.w, gv.w);
    }
    __syncthreads();

    const uint2* s2 = reinterpret_cast<const uint2*>(s_in);

    uint2 os[8], od[8];                       // per-quad packed outputs (registers)

    #pragma unroll
    for (int p = 0; p < 8; ++p) {             // pixel quad (ow = p, p+8, p+16, p+24)
        h2 x0[16], x1[16];                    // x0=(p, p+16), x1=(p+8, p+24)
        #pragma unroll
        for (int r = 0; r < 9; ++r) {
            const int kh = r / 3, kw = r % 3;
            const int iw = p - 1 + kw;        // in [-1, 8]; compile-time per body
            const int g  = iw & 7;
            const uint2 u = s2[(kh * 8 + g) * 256 + t];
            h2 a = u2h(u.x), c = u2h(u.y);    // a=(v_g, v_g+16), c=(v_g+8, v_g+24)
            h2 ta = a, tc = c;
            if (iw < 0) {                     // p=0,kw=0: x0=(0,v15), x1=(v7,v23)
                ta.x = (_Float16)0.f; ta.y = c.x;
                tc = a;
            } else if (iw > 7) {              // p=7,kw=2: x0=(v8,v24), x1=(v16,0)
                ta = c;
                tc.x = a.y; tc.y = (_Float16)0.f;
            }
            x0[r] = Bh[r] * ta;               // -> v_pk_mul_f16
            x1[r] = Bh[r] * tc;
        }
        #pragma unroll
        for (int r = 9; r < 16; ++r) {
            x0[r] = pkh(0.f, 0.f);
            x1[r] = pkh(0.f, 0.f);
        }

        // ===== pass 0: A(str256) -> B(str16) -> C(str1), stage C-layout for gather
        h16h(x0); h16h(x1);                   // round A
        #pragma unroll                        // own slots
        for (int r = 0; r < 16; ++r)
            buf2[swz(256 * r + t)] = make_uint2(h2u(x0[r]), h2u(x1[r]));
        __syncthreads();                      // RAW, cross-wave (A -> B)
        #pragma unroll
        for (int r = 0; r < 16; ++r) {
            const uint2 u = buf2[swz(256 * t1 + 16 * r + t0)];
            x0[r] = u2h(u.x); x1[r] = u2h(u.y);
        }
        h16h(x0); h16h(x1);                   // round B
        #pragma unroll                        // own slots
        for (int r = 0; r < 16; ++r)
            buf2[swz(256 * t1 + 16 * r + t0)] = make_uint2(h2u(x0[r]), h2u(x1[r]));
        // NO barrier: B->C exchange stays within group t1 = 16 contiguous threads
        // (same wave); lgkmcnt ordering suffices.
        #pragma unroll
        for (int r = 0; r < 16; ++r) {
            const uint2 u = buf2[swz(256 * t1 + 16 * t0 + r)];
            x0[r] = u2h(u.x); x1[r] = u2h(u.y);
        }
        h16h(x0); h16h(x1);                   // round C
        #pragma unroll                        // own slots (stage for gather)
        for (int r = 0; r < 16; ++r)
            buf2[swz(256 * t1 + 16 * t0 + r)] = make_uint2(h2u(x0[r]), h2u(x1[r]));
        __syncthreads();                      // RAW, cross-wave (before perm gather)

        // ===== permutation + G: gather INTO C-layout (thread t owns j = 16t+r)
        #pragma unroll
        for (int r = 0; r < 16; ++r) {
            const uint2 u = buf2[PAv[r]];
            x0[r] = Gh[r] * u2h(u.x);
            x1[r] = Gh[r] * u2h(u.y);
        }

        // ===== pass 1 (reordered): C(str1) -> B(str16) -> A(str256, truncated)
        h16h(x0); h16h(x1);                   // round C'
        __syncthreads();                      // WAR: all gathers done before overwrite
        #pragma unroll
        for (int r = 0; r < 16; ++r)
            buf2[swz(256 * t1 + 16 * t0 + r)] = make_uint2(h2u(x0[r]), h2u(x1[r]));
        // NO barrier: C->B intra-wave (group t1).
        #pragma unroll
        for (int r = 0; r < 16; ++r) {
            const uint2 u = buf2[swz(256 * t1 + 16 * r + t0)];
            x0[r] = u2h(u.x); x1[r] = u2h(u.y);
        }
        h16h(x0); h16h(x1);                   // round B'
        #pragma unroll                        // own slots
        for (int r = 0; r < 16; ++r)
            buf2[swz(256 * t1 + 16 * r + t0)] = make_uint2(h2u(x0[r]), h2u(x1[r]));
        __syncthreads();                      // RAW, cross-wave (B' -> A-layout read)
        #pragma unroll
        for (int r = 0; r < 16; ++r) {        // A-layout: x[r] = j = 256r + t
            const uint2 u = buf2[swz(256 * r + t)];
            x0[r] = u2h(u.x); x1[r] = u2h(u.y);
        }
        // truncated round A: oc = t (sum), oc = 256+t (alternating sum)
        h2 s0, d0, s1, d1;
        trunc16(x0, s0, d0);                  // (ow p, p+16)
        trunc16(x1, s1, d1);                  // (ow p+8, p+24)
        os[p] = make_uint2(h2u(s0), h2u(s1)); // static index (unrolled) -> registers
        od[p] = make_uint2(h2u(d0), h2u(d1));
        // next quad's A-write hits thread-own slots -> no WAR barrier at loop top
    }

    // ===== block-end epilogue =====
    // Repack to ow-major: U[i]/V[i] = uint2 covering cols 4i..4i+3 of rows oc=t / 256+t.
    // col w: quad p = w&7, slot k = w>>3. U[i]: k = i>>1, quads p0..p0+3, p0 = (i&1)*4.
    uint2 U[8], V[8];
    #pragma unroll
    for (int i = 0; i < 8; ++i) {
        const int k = i >> 1, p0 = (i & 1) * 4;
        h2 lo, hi;
        lo.x = slotk(os[p0], k);     lo.y = slotk(os[p0 + 1], k);
        hi.x = slotk(os[p0 + 2], k); hi.y = slotk(os[p0 + 3], k);
        U[i] = make_uint2(h2u(lo), h2u(hi));
        lo.x = slotk(od[p0], k);     lo.y = slotk(od[p0 + 1], k);
        hi.x = slotk(od[p0 + 2], k); hi.y = slotk(od[p0 + 3], k);
        V[i] = make_uint2(h2u(lo), h2u(hi));
    }

    __syncthreads();                          // WAR: quad-7 A-reads done everywhere
    // Stage rows into buf2: [oc*8 + (i ^ ((oc>>1)&7))]. For oc=t and oc=256+t the
    // swizzle term is identical ((t>>1)&7). 4-cycle-optimal b64 banking.
    {
        const int sw = (t >> 1) & 7;
        #pragma unroll
        for (int i = 0; i < 8; ++i) {
            buf2[(size_t)t * 8 + (i ^ sw)]         = U[i];
            buf2[(size_t)(256 + t) * 8 + (i ^ sw)] = V[i];
        }
    }
    __syncthreads();                          // RAW
    // Cooperative store: 16 iters; per wave-instr 8 rows x full 128B lines.
    #pragma unroll
    for (int it = 0; it < 16; ++it) {
        const int oc = it * 32 + (t >> 3);
        const int c  = t & 7;
        const uint2 u = buf2[(size_t)oc * 8 + (c ^ ((oc >> 1) & 7))];
        const h2 lo = u2h(u.x), hi = u2h(u.y);
        const float S = Sm[oc], C = bias[oc];
        const float4 v = make_float4(S * (float)lo.x + C, S * (float)lo.y + C,
                                     S * (float)hi.x + C, S * (float)hi.y + C);
        *reinterpret_cast<float4*>(
            out + ((size_t)b * 512 + oc) * 1024 + (size_t)oh * 32 + 4 * c) = v;
    }
}

extern "C" void kernel_launch(void* const* d_in, const int* in_sizes, int n_in,
                              void* d_out, int out_size, void* d_ws, size_t ws_size,
                              hipStream_t stream) {
    const float* in   = (const float*)d_in[0];
    const float* Bm   = (const float*)d_in[1];
    const float* Gm   = (const float*)d_in[2];
    const float* Sm   = (const float*)d_in[3];
    const float* bias = (const float*)d_in[4];
    const int*   P    = (const int*)d_in[5];
    float* out = (float*)d_out;
    (void)d_ws; (void)ws_size;

    dim3 grid(16 * 32), block(256);
    fastfood_kernel<<<grid, block, 0, stream>>>(in, Bm, Gm, Sm, bias, P, out);
}